// Round 6
// baseline (408.615 us; speedup 1.0000x reference)
//
#include <hip/hip_runtime.h>
#include <math.h>

#define BB 4
#define LL 1024
#define RR 4
#define DD 1024
#define NHEADS 16
#define HDIM 64
#define FFD 4096
#define EPSV 1e-6f

typedef short s16x8 __attribute__((ext_vector_type(8)));
typedef float f32x4 __attribute__((ext_vector_type(4)));
typedef unsigned short u16;

__device__ inline unsigned short f2bf(float x) {
  unsigned u = __builtin_bit_cast(unsigned, x);
  unsigned r = (u + 0x7fffu + ((u >> 16) & 1u)) >> 16;
  return (unsigned short)r;
}
__device__ inline float bf2f(u16 x) {
  return __builtin_bit_cast(float, (unsigned)x << 16);
}

__device__ inline float wred_sum(float v) {
#pragma unroll
  for (int off = 32; off; off >>= 1) v += __shfl_down(v, off);
  return v;
}

__device__ inline void gload_lds16(const u16* g, u16* l) {
  __builtin_amdgcn_global_load_lds(
      (const __attribute__((address_space(1))) unsigned int*)g,
      (__attribute__((address_space(3))) unsigned int*)l, 16, 0, 0);
}

// ---------------- fused f32 -> bf16 for the 4 weight tensors ----------------
__global__ __launch_bounds__(256) void cvt4_kernel(
    const float* __restrict__ s0, const float* __restrict__ s1,
    const float* __restrict__ s2, const float* __restrict__ s3,
    u16* __restrict__ d0, u16* __restrict__ d1,
    u16* __restrict__ d2, u16* __restrict__ d3) {
  const int n0 = 786432, n1 = 262144, n2 = 1048576, n3 = 1048576;
  const int total = n0 + n1 + n2 + n3;
  for (int i = blockIdx.x * 256 + threadIdx.x; i < total; i += gridDim.x * 256) {
    const float4* src; ushort4* dst; int j;
    if (i < n0)                { src = (const float4*)s0; dst = (ushort4*)d0; j = i; }
    else if (i < n0 + n1)      { src = (const float4*)s1; dst = (ushort4*)d1; j = i - n0; }
    else if (i < n0 + n1 + n2) { src = (const float4*)s2; dst = (ushort4*)d2; j = i - n0 - n1; }
    else                       { src = (const float4*)s3; dst = (ushort4*)d3; j = i - n0 - n1 - n2; }
    float4 v = src[j];
    ushort4 o;
    o.x = f2bf(v.x); o.y = f2bf(v.y); o.z = f2bf(v.z); o.w = f2bf(v.w);
    dst[j] = o;
  }
}

// ---------------- width (hyper-connection) kernel ----------------
// NP==0: Hs from Hin (f32). NP>0: Hs = beta*sum(NP bf16 partials) + mixrest_in(bf16)
template<int NP>
__global__ __launch_bounds__(256) void width_kernel(
    const float* __restrict__ Hin,
    const u16* mixrest_in,
    const float* __restrict__ beta_in,
    const u16* __restrict__ pp,            // NP bf16 partials, stride MN
    const float* __restrict__ hc_norm_w,
    const float* __restrict__ alpha_fn,
    const float* __restrict__ beta_fn,
    const float* __restrict__ a_scale,
    const float* __restrict__ b_scale,
    const float* __restrict__ s_alpha,
    const float* __restrict__ s_beta,
    const float* __restrict__ post_norm_w,
    u16* mixrest_out,
    float* __restrict__ beta_out,
    u16* __restrict__ x_out)
{
  const size_t MN = (size_t)4096 * 1024;
  const int bl = blockIdx.x;
  const int t = threadIdx.x;
  const int wid = t >> 6;
  __shared__ __align__(16) float Hs[4 * 1024];
  __shared__ __align__(16) float m0[1024];
  __shared__ float scr[96];
  __shared__ float alpha_s[4][5];
  __shared__ float beta_s[4];
  __shared__ float inv_s[4];
  __shared__ float inv0_s;

  if (NP > 0) {
    int d0 = t * 4;
    float4 s; s.x = 0.f; s.y = 0.f; s.z = 0.f; s.w = 0.f;
#pragma unroll
    for (int p = 0; p < (NP > 0 ? NP : 1); ++p) {
      ushort4 v = *(const ushort4*)&pp[p * MN + (size_t)bl * 1024 + d0];
      s.x += bf2f(v.x); s.y += bf2f(v.y); s.z += bf2f(v.z); s.w += bf2f(v.w);
    }
    ((float4*)m0)[t] = s;
    __syncthreads();
    for (int i = t; i < 1024; i += 256) {
      int n = i >> 8;
      float be = beta_in[bl * 4 + n];
      ushort4 mr = ((const ushort4*)(mixrest_in + (size_t)bl * 4096))[i];
      float4 ao = ((const float4*)m0)[i & 255];
      float4 hv;
      hv.x = be * ao.x + bf2f(mr.x); hv.y = be * ao.y + bf2f(mr.y);
      hv.z = be * ao.z + bf2f(mr.z); hv.w = be * ao.w + bf2f(mr.w);
      ((float4*)Hs)[i] = hv;
    }
  } else {
    for (int i = t; i < 1024; i += 256)
      ((float4*)Hs)[i] = ((const float4*)(Hin + (size_t)bl * 4096))[i];
  }
  __syncthreads();

  float ss[4];
#pragma unroll
  for (int n = 0; n < 4; ++n) {
    float a = 0.f;
    for (int d = t; d < 1024; d += 256) { float v = Hs[n * 1024 + d]; a += v * v; }
    ss[n] = a;
  }
#pragma unroll
  for (int n = 0; n < 4; ++n) {
    float r = wred_sum(ss[n]);
    if ((t & 63) == 0) scr[wid * 4 + n] = r;
  }
  __syncthreads();
  if (t < 4) {
    float tot = scr[t] + scr[4 + t] + scr[8 + t] + scr[12 + t];
    inv_s[t] = 1.f / (sqrtf(tot * (1.f / 1024.f)) + EPSV);
  }
  __syncthreads();
  float inv[4] = {inv_s[0], inv_s[1], inv_s[2], inv_s[3]};

  float dots[4][6];
#pragma unroll
  for (int n = 0; n < 4; ++n)
#pragma unroll
    for (int k = 0; k < 6; ++k) dots[n][k] = 0.f;
  for (int d = t; d < 1024; d += 256) {
    float w = hc_norm_w[d];
    float a0 = alpha_fn[d * 5 + 0], a1 = alpha_fn[d * 5 + 1], a2 = alpha_fn[d * 5 + 2],
          a3 = alpha_fn[d * 5 + 3], a4 = alpha_fn[d * 5 + 4];
    float bfv = beta_fn[d];
#pragma unroll
    for (int n = 0; n < 4; ++n) {
      float nh = Hs[n * 1024 + d] * w * inv[n];
      dots[n][0] += nh * a0; dots[n][1] += nh * a1; dots[n][2] += nh * a2;
      dots[n][3] += nh * a3; dots[n][4] += nh * a4; dots[n][5] += nh * bfv;
    }
  }
  __syncthreads();
#pragma unroll
  for (int n = 0; n < 4; ++n)
#pragma unroll
    for (int k = 0; k < 6; ++k) {
      float r = wred_sum(dots[n][k]);
      if ((t & 63) == 0) scr[wid * 24 + n * 6 + k] = r;
    }
  __syncthreads();
  if (t < 24) {
    float raw = scr[t] + scr[24 + t] + scr[48 + t] + scr[72 + t];
    int n = t / 6, k = t % 6;
    if (k < 5) alpha_s[n][k] = tanhf(raw) * a_scale[0] + s_alpha[n * 5 + k];
    else       beta_s[n]     = tanhf(raw) * b_scale[0] + s_beta[n];
  }
  __syncthreads();

  {
    int i = t;
    float4 h0 = ((const float4*)Hs)[i];
    float4 h1 = ((const float4*)Hs)[256 + i];
    float4 h2 = ((const float4*)Hs)[512 + i];
    float4 h3 = ((const float4*)Hs)[768 + i];
#pragma unroll
    for (int k = 0; k < 5; ++k) {
      float c0 = alpha_s[0][k], c1 = alpha_s[1][k], c2 = alpha_s[2][k], c3 = alpha_s[3][k];
      float4 mv;
      mv.x = c0 * h0.x + c1 * h1.x + c2 * h2.x + c3 * h3.x;
      mv.y = c0 * h0.y + c1 * h1.y + c2 * h2.y + c3 * h3.y;
      mv.z = c0 * h0.z + c1 * h1.z + c2 * h2.z + c3 * h3.z;
      mv.w = c0 * h0.w + c1 * h1.w + c2 * h2.w + c3 * h3.w;
      if (k == 0) {
        ((float4*)m0)[i] = mv;
      } else {
        ushort4 ov;
        ov.x = f2bf(mv.x); ov.y = f2bf(mv.y); ov.z = f2bf(mv.z); ov.w = f2bf(mv.w);
        ((ushort4*)(mixrest_out + (size_t)bl * 4096 + (size_t)(k - 1) * 1024))[i] = ov;
      }
    }
  }
  if (t < 4) beta_out[bl * 4 + t] = beta_s[t];
  __syncthreads();

  {
    float a = 0.f;
    for (int d = t; d < 1024; d += 256) { float v = m0[d]; a += v * v; }
    float r = wred_sum(a);
    if ((t & 63) == 0) scr[wid] = r;
  }
  __syncthreads();
  if (t == 0) {
    float tot = scr[0] + scr[1] + scr[2] + scr[3];
    inv0_s = 1.f / (sqrtf(tot * (1.f / 1024.f)) + EPSV);
  }
  __syncthreads();
  {
    float iv = inv0_s;
    float4 mv = ((const float4*)m0)[t];
    float4 wv = ((const float4*)post_norm_w)[t];
    ushort4 ov;
    ov.x = f2bf(wv.x * mv.x * iv);
    ov.y = f2bf(wv.y * mv.y * iv);
    ov.z = f2bf(wv.z * mv.z * iv);
    ov.w = f2bf(wv.w * mv.w * iv);
    ((ushort4*)(x_out + (size_t)bl * 1024))[t] = ov;
  }
}

// ---------------- 256x256 8-phase bf16 GEMM: C[M,N] = A[M,K] @ W[N,K]^T ----------------
// 512 thr / 8 waves (2M x 4N); wave tile 128x64; BK=64; LDS 128KB dbuf.
// Per phase: gate -> barrier -> stage 2x global_load_lds -> ds_read frags -> lgkmcnt(0)
// -> setprio(1) -> 16 MFMA -> setprio(0). Counted vmcnt; never drains mid-loop.
// LDS swizzle: 16B chunk' = chunk ^ (row&7) (2-way conflict = free).
// EPI=0: (SPLIT>1) bf16 partials at Cb + sK*M*N; EPI=1: gelu->bf16; EPI=2: qkv split.
template<int EPI, int SPLIT>
__global__ __launch_bounds__(512, 1) void gemm256_kernel(
    const u16* __restrict__ A, const u16* __restrict__ W,
    u16* __restrict__ Cb, u16* __restrict__ Vt,
    int M, int N, int K)
{
  __shared__ __align__(16) u16 As[2][256 * 64];
  __shared__ __align__(16) u16 Bs[2][256 * 64];
  const int tn = N >> 8, tm = M >> 8;
  int bid = blockIdx.x;
  const int nwg = gridDim.x;
  bid = (bid & 7) * (nwg >> 3) + (bid >> 3);  // XCD swizzle (nwg % 8 == 0)
  const int ts = tm * tn;
  const int sK = bid / ts;
  const int tb = bid - sK * ts;
  const int bm = tb / tn, bn = tb % tn;
  const int Kc = K / SPLIT;
  const int kbeg = sK * Kc;

  const int t = threadIdx.x, l = t & 63, w = t >> 6;
  const int wr = w >> 2, wc = w & 3;
  const int m0g = bm << 8, n0g = bn << 8;
  const int fr = l & 15, g4 = l >> 4;

  // staging: issue covers 64 rows; thread: row = rbase + (t>>3), dest = linear t*16B,
  // global chunk pre-swizzled so swizzled ds_read retrieves correct data.
  const int srow = t >> 3;
  const int gsc8 = (((t & 7) ^ (srow & 7)) << 3);
  const u16* pA = A + (size_t)(m0g + srow) * K + kbeg + gsc8;
  const u16* pB = W + (size_t)(n0g + srow) * K + kbeg + gsc8;

#define STG_A(rb, buf, ko) gload_lds16(pA + (size_t)(rb) * K + (ko), &As[buf][(rb) * 64 + (t << 3)])
#define STG_B(rb, buf, ko) gload_lds16(pB + (size_t)(rb) * K + (ko), &Bs[buf][(rb) * 64 + (t << 3)])
#define LDA(dst, mh, kk)                                                                   \
  {                                                                                        \
    _Pragma("unroll") for (int j = 0; j < 4; ++j)                                          \
        dst[j] = *(const s16x8*)(&As[c][(wr * 128 + ((mh)*4 + j) * 16 + fr) * 64 +         \
                                        ((((kk)*4 + g4) ^ (fr & 7)) << 3)]);               \
  }
#define LDB(dst, kk)                                                                       \
  {                                                                                        \
    _Pragma("unroll") for (int n = 0; n < 4; ++n)                                          \
        dst[n] = *(const s16x8*)(&Bs[c][(wc * 64 + n * 16 + fr) * 64 +                     \
                                        ((((kk)*4 + g4) ^ (fr & 7)) << 3)]);               \
  }
#define MM(mh, BF)                                                                         \
  _Pragma("unroll") for (int j = 0; j < 4; ++j)                                            \
      _Pragma("unroll") for (int n = 0; n < 4; ++n)                                        \
          acc[(mh)*4 + j][n] =                                                             \
              __builtin_amdgcn_mfma_f32_16x16x32_bf16(af[j], BF[n], acc[(mh)*4 + j][n], 0, 0, 0);
#define LGKM0                                            \
  asm volatile("s_waitcnt lgkmcnt(0)" ::: "memory");     \
  __builtin_amdgcn_sched_barrier(0)
#define BAR                                              \
  __builtin_amdgcn_s_barrier();                          \
  __builtin_amdgcn_sched_barrier(0)

  f32x4 acc[8][4];
#pragma unroll
  for (int i = 0; i < 8; ++i)
#pragma unroll
    for (int j = 0; j < 4; ++j)
#pragma unroll
      for (int e = 0; e < 4; ++e) acc[i][j][e] = 0.f;

  const int nt = Kc >> 6;
  // prologue: tile 0 -> buf 0 (same order as in-loop)
  STG_B(0, 0, 0); STG_B(64, 0, 0);
  STG_B(128, 0, 0); STG_B(192, 0, 0);
  STG_A(0, 0, 0); STG_A(128, 0, 0);
  STG_A(64, 0, 0); STG_A(192, 0, 0);

  int c = 0;
  for (int kt = 0; kt < nt; ++kt) {
    const bool st = (kt + 1 < nt);
    const int ko = (kt + 1) << 6;
    const int nb = c ^ 1;
    s16x8 af[4], bf0[4], bf1[4];
    // ph0 (kk0, mh0) -- gate: all B(t) + A-mh0(t) landed (2 youngest = A-mh1 allowed out)
    asm volatile("s_waitcnt vmcnt(2)" ::: "memory");
    BAR;
    if (st) { STG_B(0, nb, ko); STG_B(64, nb, ko); }
    LDA(af, 0, 0); LDB(bf0, 0);
    LGKM0;
    __builtin_amdgcn_s_setprio(1); MM(0, bf0); __builtin_amdgcn_s_setprio(0);
    // ph1 (kk1, mh0)
    BAR;
    if (st) { STG_B(128, nb, ko); STG_B(192, nb, ko); }
    LDA(af, 0, 1); LDB(bf1, 1);
    LGKM0;
    __builtin_amdgcn_s_setprio(1); MM(0, bf1); __builtin_amdgcn_s_setprio(0);
    // ph2 (kk0, mh1) -- gate: A-mh1(t) landed (4 youngest = this tile's B stages allowed out)
    if (st) asm volatile("s_waitcnt vmcnt(4)" ::: "memory");
    else    asm volatile("s_waitcnt vmcnt(0)" ::: "memory");
    BAR;
    if (st) { STG_A(0, nb, ko); STG_A(128, nb, ko); }
    LDA(af, 1, 0);
    LGKM0;
    __builtin_amdgcn_s_setprio(1); MM(1, bf0); __builtin_amdgcn_s_setprio(0);
    // ph3 (kk1, mh1)
    BAR;
    if (st) { STG_A(64, nb, ko); STG_A(192, nb, ko); }
    LDA(af, 1, 1);
    LGKM0;
    __builtin_amdgcn_s_setprio(1); MM(1, bf1); __builtin_amdgcn_s_setprio(0);
    c = nb;
  }
#undef STG_A
#undef STG_B
#undef LDA
#undef LDB
#undef MM
#undef LGKM0
#undef BAR

  const int rb = m0g + wr * 128 + (g4 << 2);
  const int cb = n0g + wc * 64 + fr;
  if (SPLIT > 1) {
    u16* Cp = Cb + (size_t)sK * M * N;
#pragma unroll
    for (int m = 0; m < 8; ++m)
#pragma unroll
      for (int n = 0; n < 4; ++n)
#pragma unroll
        for (int j = 0; j < 4; ++j)
          Cp[(size_t)(rb + m * 16 + j) * N + cb + n * 16] = f2bf(acc[m][n][j]);
  } else {
#pragma unroll
    for (int m = 0; m < 8; ++m)
#pragma unroll
      for (int n = 0; n < 4; ++n) {
        if (EPI == 2 && n0g >= 2048) {
          int cc = cb + n * 16 - 2048;
          int hh = cc >> 6, dd = cc & 63;
          int r0 = rb + m * 16;
          ushort4 ov;
          ov.x = f2bf(acc[m][n][0]); ov.y = f2bf(acc[m][n][1]);
          ov.z = f2bf(acc[m][n][2]); ov.w = f2bf(acc[m][n][3]);
          *(ushort4*)&Vt[((size_t)((r0 >> 10) * 16 + hh) * 64 + dd) * 1024 + (r0 & 1023)] = ov;
        } else {
#pragma unroll
          for (int j = 0; j < 4; ++j) {
            int r = rb + m * 16 + j;
            int cidx = cb + n * 16;
            float v = acc[m][n][j];
            if (EPI == 1) {
              v = 0.5f * v * (1.f + erff(v * 0.70710678118f));
              Cb[(size_t)r * N + cidx] = f2bf(v);
            } else if (EPI == 2) {
              Cb[(size_t)r * 2048 + cidx] = f2bf(v);
            } else {
              Cb[(size_t)r * N + cidx] = f2bf(v);
            }
          }
        }
      }
  }
}

// ---------------- MFMA flash attention, causal ----------------
__global__ __launch_bounds__(256) void attn_mfma_kernel(
    const u16* __restrict__ qk, const u16* __restrict__ Vt, u16* __restrict__ out)
{
  const int h = blockIdx.y, b = blockIdx.z;
  const int qt = (h & 1) ? (15 - blockIdx.x) : blockIdx.x;
  const int t = threadIdx.x, l = t & 63, w = t >> 6;
  const int q0 = qt << 6;
  __shared__ __align__(16) u16 Ks[64 * 64];
  __shared__ __align__(16) u16 Vs[64 * 64];
  __shared__ __align__(16) u16 Ps[4][16 * 64];

  const int fr = l & 15;
  const int fg = (l >> 4) << 3;
  const int fswz = (fr & 7) << 3;

  const int qrow = q0 + w * 16 + fr;
  const size_t qbase = (size_t)(b * 1024 + qrow) * 2048 + h * 64 + fg;
  const s16x8 aq0 = *(const s16x8*)(qk + qbase);
  const s16x8 aq1 = *(const s16x8*)(qk + qbase + 32);

  f32x4 acc_o[4];
#pragma unroll
  for (int i = 0; i < 4; ++i)
#pragma unroll
    for (int e = 0; e < 4; ++e) acc_o[i][e] = 0.f;
  float m_i[4] = {-INFINITY, -INFINITY, -INFINITY, -INFINITY};
  float l_i[4] = {0.f, 0.f, 0.f, 0.f};

  const int srow = t >> 2;
  const int sc = (t & 3) << 4;
  const int c0s = sc ^ ((srow & 7) << 3);
  const int c1s = (sc + 8) ^ ((srow & 7) << 3);
  const int qrow_c = q0 + w * 16 + ((l >> 4) << 2);
  u16* Psw = &Ps[w][0];
  const int nkt = qt + 1;

  for (int kt = 0; kt < nkt; ++kt) {
    const int kb = kt << 6;
    __syncthreads();
    {
      size_t kg = (size_t)(b * 1024 + kb + srow) * 2048 + 1024 + h * 64 + sc;
      s16x8 kv0 = *(const s16x8*)(qk + kg);
      s16x8 kv1 = *(const s16x8*)(qk + kg + 8);
      size_t vg = (size_t)((b * 16 + h) * 64 + srow) * 1024 + kb + sc;
      s16x8 vv0 = *(const s16x8*)(Vt + vg);
      s16x8 vv1 = *(const s16x8*)(Vt + vg + 8);
      *(s16x8*)(Ks + srow * 64 + c0s) = kv0;
      *(s16x8*)(Ks + srow * 64 + c1s) = kv1;
      *(s16x8*)(Vs + srow * 64 + c0s) = vv0;
      *(s16x8*)(Vs + srow * 64 + c1s) = vv1;
    }
    __syncthreads();

    f32x4 s[4];
#pragma unroll
    for (int n = 0; n < 4; ++n) {
#pragma unroll
      for (int e = 0; e < 4; ++e) s[n][e] = 0.f;
      s16x8 bk0 = *(const s16x8*)(Ks + (n * 16 + fr) * 64 + (fg ^ fswz));
      s16x8 bk1 = *(const s16x8*)(Ks + (n * 16 + fr) * 64 + ((32 + fg) ^ fswz));
      s[n] = __builtin_amdgcn_mfma_f32_16x16x32_bf16(aq0, bk0, s[n], 0, 0, 0);
      s[n] = __builtin_amdgcn_mfma_f32_16x16x32_bf16(aq1, bk1, s[n], 0, 0, 0);
    }
#pragma unroll
    for (int n = 0; n < 4; ++n)
#pragma unroll
      for (int e = 0; e < 4; ++e) s[n][e] *= 0.125f;
    if (kt == qt) {
#pragma unroll
      for (int n = 0; n < 4; ++n) {
        int kc = kb + n * 16 + fr;
#pragma unroll
        for (int r = 0; r < 4; ++r)
          if (kc > qrow_c + r) s[n][r] = -INFINITY;
      }
    }

    float rm[4], fac[4];
#pragma unroll
    for (int r = 0; r < 4; ++r)
      rm[r] = fmaxf(fmaxf(s[0][r], s[1][r]), fmaxf(s[2][r], s[3][r]));
#pragma unroll
    for (int off = 1; off < 16; off <<= 1)
#pragma unroll
      for (int r = 0; r < 4; ++r) rm[r] = fmaxf(rm[r], __shfl_xor(rm[r], off));
#pragma unroll
    for (int r = 0; r < 4; ++r) {
      float mn = fmaxf(m_i[r], rm[r]);
      fac[r] = __expf(m_i[r] - mn);
      m_i[r] = mn;
    }
    float rs[4] = {0.f, 0.f, 0.f, 0.f};
    float pb[4][4];
#pragma unroll
    for (int n = 0; n < 4; ++n)
#pragma unroll
      for (int r = 0; r < 4; ++r) {
        float pv = __expf(s[n][r] - m_i[r]);
        pb[n][r] = pv;
        rs[r] += pv;
      }
#pragma unroll
    for (int off = 1; off < 16; off <<= 1)
#pragma unroll
      for (int r = 0; r < 4; ++r) rs[r] += __shfl_xor(rs[r], off);
#pragma unroll
    for (int r = 0; r < 4; ++r) l_i[r] = l_i[r] * fac[r] + rs[r];
#pragma unroll
    for (int dt = 0; dt < 4; ++dt)
#pragma unroll
      for (int r = 0; r < 4; ++r) acc_o[dt][r] *= fac[r];

#pragma unroll
    for (int n = 0; n < 4; ++n)
#pragma unroll
      for (int r = 0; r < 4; ++r) {
        int prow = ((l >> 4) << 2) + r;
        Psw[prow * 64 + ((n * 16 + fr) ^ ((prow & 7) << 3))] = f2bf(pb[n][r]);
      }
    asm volatile("s_waitcnt lgkmcnt(0)" ::: "memory");
    __builtin_amdgcn_sched_barrier(0);

    s16x8 pa0 = *(const s16x8*)(Psw + fr * 64 + (fg ^ fswz));
    s16x8 pa1 = *(const s16x8*)(Psw + fr * 64 + ((32 + fg) ^ fswz));
#pragma unroll
    for (int dt = 0; dt < 4; ++dt) {
      s16x8 bv0 = *(const s16x8*)(Vs + (dt * 16 + fr) * 64 + (fg ^ fswz));
      s16x8 bv1 = *(const s16x8*)(Vs + (dt * 16 + fr) * 64 + ((32 + fg) ^ fswz));
      acc_o[dt] = __builtin_amdgcn_mfma_f32_16x16x32_bf16(pa0, bv0, acc_o[dt], 0, 0, 0);
      acc_o[dt] = __builtin_amdgcn_mfma_f32_16x16x32_bf16(pa1, bv1, acc_o[dt], 0, 0, 0);
    }
  }

  float invl[4];
#pragma unroll
  for (int r = 0; r < 4; ++r) invl[r] = 1.f / l_i[r];
#pragma unroll
  for (int dt = 0; dt < 4; ++dt)
#pragma unroll
    for (int r = 0; r < 4; ++r) {
      size_t idx = (size_t)(b * 1024 + qrow_c + r) * 1024 + h * 64 + dt * 16 + fr;
      out[idx] = f2bf(acc_o[dt][r] * invl[r]);
    }
}

// ---------------- final depth-2 (sums NPART bf16 partials + bf16 mixrest) ----------------
template<int NPART>
__global__ __launch_bounds__(256) void depth2_kernel(
    const u16* __restrict__ parts, const u16* __restrict__ mixrest,
    const float* __restrict__ beta, float* __restrict__ Hout)
{
  const size_t MN = (size_t)4096 * 1024;
  const size_t stride = (size_t)gridDim.x * 256;
  const size_t n8 = (size_t)BB * LL * RR * DD / 8;
  for (size_t i = (size_t)blockIdx.x * 256 + threadIdx.x; i < n8; i += stride) {
    size_t e = i * 8;
    int d = (int)(e & 1023);
    int n = (int)((e >> 10) & 3);
    size_t bl = e >> 12;
    float be = beta[bl * 4 + n];
    float f[8];
#pragma unroll
    for (int j = 0; j < 8; ++j) f[j] = 0.f;
#pragma unroll
    for (int p = 0; p < NPART; ++p) {
      s16x8 v = *(const s16x8*)&parts[p * MN + bl * 1024 + d];
#pragma unroll
      for (int j = 0; j < 8; ++j) f[j] += bf2f((u16)v[j]);
    }
    s16x8 m = *(const s16x8*)&mixrest[e];
    float4 o0, o1;
    o0.x = be * f[0] + bf2f((u16)m[0]); o0.y = be * f[1] + bf2f((u16)m[1]);
    o0.z = be * f[2] + bf2f((u16)m[2]); o0.w = be * f[3] + bf2f((u16)m[3]);
    o1.x = be * f[4] + bf2f((u16)m[4]); o1.y = be * f[5] + bf2f((u16)m[5]);
    o1.z = be * f[6] + bf2f((u16)m[6]); o1.w = be * f[7] + bf2f((u16)m[7]);
    *(float4*)&Hout[e] = o0;
    *(float4*)&Hout[e + 4] = o1;
  }
}

extern "C" void kernel_launch(void* const* d_in, const int* in_sizes, int n_in,
                              void* d_out, int out_size, void* d_ws, size_t ws_size,
                              hipStream_t stream) {
  const float* H       = (const float*)d_in[0];
  const float* hc1_nw  = (const float*)d_in[1];
  const float* hc1_afn = (const float*)d_in[2];
  const float* hc1_bfn = (const float*)d_in[3];
  const float* hc1_as  = (const float*)d_in[4];
  const float* hc1_bs  = (const float*)d_in[5];
  const float* hc1_sa  = (const float*)d_in[6];
  const float* hc1_sb  = (const float*)d_in[7];
  const float* attn_nw = (const float*)d_in[8];
  const float* qkv_w   = (const float*)d_in[9];
  const float* out_w   = (const float*)d_in[10];
  const float* hc2_nw  = (const float*)d_in[11];
  const float* hc2_afn = (const float*)d_in[12];
  const float* hc2_bfn = (const float*)d_in[13];
  const float* hc2_as  = (const float*)d_in[14];
  const float* hc2_bs  = (const float*)d_in[15];
  const float* hc2_sa  = (const float*)d_in[16];
  const float* hc2_sb  = (const float*)d_in[17];
  const float* ffn_nw  = (const float*)d_in[18];
  const float* fc1_w   = (const float*)d_in[19];
  const float* fc2_w   = (const float*)d_in[20];
  float* Hout = (float*)d_out;

  char* wsp = (char*)d_ws;
  size_t off = 0;
  auto carve = [&](size_t bytes) {
    void* p = wsp + off;
    off = (off + bytes + 255) & ~(size_t)255;
    return p;
  };
  const size_t MN = (size_t)4096 * 1024;
  u16* wq_bf   = (u16*)carve((size_t)3072 * 1024 * 2);
  u16* wo_bf   = (u16*)carve((size_t)1024 * 1024 * 2);
  u16* w1_bf   = (u16*)carve((size_t)4096 * 1024 * 2);
  u16* w2_bf   = (u16*)carve((size_t)4096 * 1024 * 2);
  u16* xbf     = (u16*)carve((size_t)4096 * 1024 * 2);
  u16* mixrest = (u16*)carve((size_t)4096 * 4096 * 2);   // bf16 now
  float* beta1 = (float*)carve((size_t)16384 * 4);
  float* beta2 = (float*)carve((size_t)16384 * 4);
  char* uregion = (char*)carve((size_t)32 * 1024 * 1024);
  u16* qk_bf   = (u16*)uregion;
  u16* Vt      = (u16*)(uregion + (size_t)16 * 1024 * 1024);
  u16* g1_bf   = (u16*)uregion;
  u16* attn_bf = (u16*)carve((size_t)4096 * 1024 * 2);
  u16* pp      = (u16*)carve((size_t)4 * MN * 2);        // 4 bf16 partials (shared region)

  // 1. weights -> bf16 (fused)
  cvt4_kernel<<<2048, 256, 0, stream>>>(qkv_w, out_w, fc1_w, fc2_w, wq_bf, wo_bf, w1_bf, w2_bf);
  // 2. width1 (+ pre-attn RMS)
  width_kernel<0><<<4096, 256, 0, stream>>>(H, nullptr, nullptr, nullptr,
      hc1_nw, hc1_afn, hc1_bfn, hc1_as, hc1_bs, hc1_sa, hc1_sb, attn_nw,
      mixrest, beta1, xbf);
  // 3. qkv -> bf16 Q,K + transposed V (192 tiles)
  gemm256_kernel<2, 1><<<192, 512, 0, stream>>>(xbf, wq_bf, qk_bf, Vt, 4096, 3072, 1024);
  // 4. attention (MFMA flash)
  attn_mfma_kernel<<<dim3(16, 16, 4), 256, 0, stream>>>(qk_bf, Vt, attn_bf);
  // 5. out projection, split-K=4 -> bf16 partials (256 blocks)
  gemm256_kernel<0, 4><<<256, 512, 0, stream>>>(attn_bf, wo_bf, pp, nullptr, 4096, 1024, 1024);
  // 6. depth1 + width2 (+ pre-ffn RMS); mixrest in-place
  width_kernel<4><<<4096, 256, 0, stream>>>(nullptr, mixrest, beta1, pp,
      hc2_nw, hc2_afn, hc2_bfn, hc2_as, hc2_bs, hc2_sa, hc2_sb, ffn_nw,
      mixrest, beta2, xbf);
  // 7. fc1 + gelu -> bf16 (256 tiles)
  gemm256_kernel<1, 1><<<256, 512, 0, stream>>>(xbf, w1_bf, g1_bf, nullptr, 4096, 4096, 1024);
  // 8. fc2, split-K=4 -> bf16 partials (256 blocks)
  gemm256_kernel<0, 4><<<256, 512, 0, stream>>>(g1_bf, w2_bf, pp, nullptr, 4096, 1024, 4096);
  // 9. depth2 -> output
  depth2_kernel<4><<<4096, 256, 0, stream>>>(pp, mixrest, beta2, Hout);
}

// Round 7
// 351.482 us; speedup vs baseline: 1.1625x; 1.1625x over previous
//
#include <hip/hip_runtime.h>
#include <math.h>

#define BB 4
#define LL 1024
#define RR 4
#define DD 1024
#define NHEADS 16
#define HDIM 64
#define FFD 4096
#define EPSV 1e-6f

typedef short s16x8 __attribute__((ext_vector_type(8)));
typedef float f32x4 __attribute__((ext_vector_type(4)));
typedef unsigned short u16;

__device__ inline unsigned short f2bf(float x) {
  unsigned u = __builtin_bit_cast(unsigned, x);
  unsigned r = (u + 0x7fffu + ((u >> 16) & 1u)) >> 16;
  return (unsigned short)r;
}
__device__ inline float bf2f(u16 x) {
  return __builtin_bit_cast(float, (unsigned)x << 16);
}

__device__ inline float wred_sum(float v) {
#pragma unroll
  for (int off = 32; off; off >>= 1) v += __shfl_down(v, off);
  return v;
}

__device__ inline void gload_lds16(const u16* g, u16* l) {
  __builtin_amdgcn_global_load_lds(
      (const __attribute__((address_space(1))) unsigned int*)g,
      (__attribute__((address_space(3))) unsigned int*)l, 16, 0, 0);
}

// ---------------- fused f32 -> bf16 for the 4 weight tensors ----------------
__global__ __launch_bounds__(256) void cvt4_kernel(
    const float* __restrict__ s0, const float* __restrict__ s1,
    const float* __restrict__ s2, const float* __restrict__ s3,
    u16* __restrict__ d0, u16* __restrict__ d1,
    u16* __restrict__ d2, u16* __restrict__ d3) {
  const int n0 = 786432, n1 = 262144, n2 = 1048576, n3 = 1048576;
  const int total = n0 + n1 + n2 + n3;
  for (int i = blockIdx.x * 256 + threadIdx.x; i < total; i += gridDim.x * 256) {
    const float4* src; ushort4* dst; int j;
    if (i < n0)                { src = (const float4*)s0; dst = (ushort4*)d0; j = i; }
    else if (i < n0 + n1)      { src = (const float4*)s1; dst = (ushort4*)d1; j = i - n0; }
    else if (i < n0 + n1 + n2) { src = (const float4*)s2; dst = (ushort4*)d2; j = i - n0 - n1; }
    else                       { src = (const float4*)s3; dst = (ushort4*)d3; j = i - n0 - n1 - n2; }
    float4 v = src[j];
    ushort4 o;
    o.x = f2bf(v.x); o.y = f2bf(v.y); o.z = f2bf(v.z); o.w = f2bf(v.w);
    dst[j] = o;
  }
}

// ---------------- width (hyper-connection) kernel ----------------
// NP==0: Hs from Hin (f32). NP>0: Hs = beta*sum(NP bf16 partials) + mixrest_in(bf16)
template<int NP>
__global__ __launch_bounds__(256) void width_kernel(
    const float* __restrict__ Hin,
    const u16* mixrest_in,
    const float* __restrict__ beta_in,
    const u16* __restrict__ pp,            // NP bf16 partials, stride MN
    const float* __restrict__ hc_norm_w,
    const float* __restrict__ alpha_fn,
    const float* __restrict__ beta_fn,
    const float* __restrict__ a_scale,
    const float* __restrict__ b_scale,
    const float* __restrict__ s_alpha,
    const float* __restrict__ s_beta,
    const float* __restrict__ post_norm_w,
    u16* mixrest_out,
    float* __restrict__ beta_out,
    u16* __restrict__ x_out)
{
  const size_t MN = (size_t)4096 * 1024;
  const int bl = blockIdx.x;
  const int t = threadIdx.x;
  const int wid = t >> 6;
  __shared__ __align__(16) float Hs[4 * 1024];
  __shared__ __align__(16) float m0[1024];
  __shared__ float scr[96];
  __shared__ float alpha_s[4][5];
  __shared__ float beta_s[4];
  __shared__ float inv_s[4];
  __shared__ float inv0_s;

  if (NP > 0) {
    int d0 = t * 4;
    float4 s; s.x = 0.f; s.y = 0.f; s.z = 0.f; s.w = 0.f;
#pragma unroll
    for (int p = 0; p < (NP > 0 ? NP : 1); ++p) {
      ushort4 v = *(const ushort4*)&pp[p * MN + (size_t)bl * 1024 + d0];
      s.x += bf2f(v.x); s.y += bf2f(v.y); s.z += bf2f(v.z); s.w += bf2f(v.w);
    }
    ((float4*)m0)[t] = s;
    __syncthreads();
    for (int i = t; i < 1024; i += 256) {
      int n = i >> 8;
      float be = beta_in[bl * 4 + n];
      ushort4 mr = ((const ushort4*)(mixrest_in + (size_t)bl * 4096))[i];
      float4 ao = ((const float4*)m0)[i & 255];
      float4 hv;
      hv.x = be * ao.x + bf2f(mr.x); hv.y = be * ao.y + bf2f(mr.y);
      hv.z = be * ao.z + bf2f(mr.z); hv.w = be * ao.w + bf2f(mr.w);
      ((float4*)Hs)[i] = hv;
    }
  } else {
    for (int i = t; i < 1024; i += 256)
      ((float4*)Hs)[i] = ((const float4*)(Hin + (size_t)bl * 4096))[i];
  }
  __syncthreads();

  float ss[4];
#pragma unroll
  for (int n = 0; n < 4; ++n) {
    float a = 0.f;
    for (int d = t; d < 1024; d += 256) { float v = Hs[n * 1024 + d]; a += v * v; }
    ss[n] = a;
  }
#pragma unroll
  for (int n = 0; n < 4; ++n) {
    float r = wred_sum(ss[n]);
    if ((t & 63) == 0) scr[wid * 4 + n] = r;
  }
  __syncthreads();
  if (t < 4) {
    float tot = scr[t] + scr[4 + t] + scr[8 + t] + scr[12 + t];
    inv_s[t] = 1.f / (sqrtf(tot * (1.f / 1024.f)) + EPSV);
  }
  __syncthreads();
  float inv[4] = {inv_s[0], inv_s[1], inv_s[2], inv_s[3]};

  float dots[4][6];
#pragma unroll
  for (int n = 0; n < 4; ++n)
#pragma unroll
    for (int k = 0; k < 6; ++k) dots[n][k] = 0.f;
  for (int d = t; d < 1024; d += 256) {
    float w = hc_norm_w[d];
    float a0 = alpha_fn[d * 5 + 0], a1 = alpha_fn[d * 5 + 1], a2 = alpha_fn[d * 5 + 2],
          a3 = alpha_fn[d * 5 + 3], a4 = alpha_fn[d * 5 + 4];
    float bfv = beta_fn[d];
#pragma unroll
    for (int n = 0; n < 4; ++n) {
      float nh = Hs[n * 1024 + d] * w * inv[n];
      dots[n][0] += nh * a0; dots[n][1] += nh * a1; dots[n][2] += nh * a2;
      dots[n][3] += nh * a3; dots[n][4] += nh * a4; dots[n][5] += nh * bfv;
    }
  }
  __syncthreads();
#pragma unroll
  for (int n = 0; n < 4; ++n)
#pragma unroll
    for (int k = 0; k < 6; ++k) {
      float r = wred_sum(dots[n][k]);
      if ((t & 63) == 0) scr[wid * 24 + n * 6 + k] = r;
    }
  __syncthreads();
  if (t < 24) {
    float raw = scr[t] + scr[24 + t] + scr[48 + t] + scr[72 + t];
    int n = t / 6, k = t % 6;
    if (k < 5) alpha_s[n][k] = tanhf(raw) * a_scale[0] + s_alpha[n * 5 + k];
    else       beta_s[n]     = tanhf(raw) * b_scale[0] + s_beta[n];
  }
  __syncthreads();

  {
    int i = t;
    float4 h0 = ((const float4*)Hs)[i];
    float4 h1 = ((const float4*)Hs)[256 + i];
    float4 h2 = ((const float4*)Hs)[512 + i];
    float4 h3 = ((const float4*)Hs)[768 + i];
#pragma unroll
    for (int k = 0; k < 5; ++k) {
      float c0 = alpha_s[0][k], c1 = alpha_s[1][k], c2 = alpha_s[2][k], c3 = alpha_s[3][k];
      float4 mv;
      mv.x = c0 * h0.x + c1 * h1.x + c2 * h2.x + c3 * h3.x;
      mv.y = c0 * h0.y + c1 * h1.y + c2 * h2.y + c3 * h3.y;
      mv.z = c0 * h0.z + c1 * h1.z + c2 * h2.z + c3 * h3.z;
      mv.w = c0 * h0.w + c1 * h1.w + c2 * h2.w + c3 * h3.w;
      if (k == 0) {
        ((float4*)m0)[i] = mv;
      } else {
        ushort4 ov;
        ov.x = f2bf(mv.x); ov.y = f2bf(mv.y); ov.z = f2bf(mv.z); ov.w = f2bf(mv.w);
        ((ushort4*)(mixrest_out + (size_t)bl * 4096 + (size_t)(k - 1) * 1024))[i] = ov;
      }
    }
  }
  if (t < 4) beta_out[bl * 4 + t] = beta_s[t];
  __syncthreads();

  {
    float a = 0.f;
    for (int d = t; d < 1024; d += 256) { float v = m0[d]; a += v * v; }
    float r = wred_sum(a);
    if ((t & 63) == 0) scr[wid] = r;
  }
  __syncthreads();
  if (t == 0) {
    float tot = scr[0] + scr[1] + scr[2] + scr[3];
    inv0_s = 1.f / (sqrtf(tot * (1.f / 1024.f)) + EPSV);
  }
  __syncthreads();
  {
    float iv = inv0_s;
    float4 mv = ((const float4*)m0)[t];
    float4 wv = ((const float4*)post_norm_w)[t];
    ushort4 ov;
    ov.x = f2bf(wv.x * mv.x * iv);
    ov.y = f2bf(wv.y * mv.y * iv);
    ov.z = f2bf(wv.z * mv.z * iv);
    ov.w = f2bf(wv.w * mv.w * iv);
    ((ushort4*)(x_out + (size_t)bl * 1024))[t] = ov;
  }
}

// ---------------- bf16 GEMM 128x128: C[M,N] = A[M,K] @ W[N,K]^T ----------------
// R4 skeleton (2-buf, counted vmcnt, raw barriers) + LDS-transpose coalesced epilogue.
// All outputs bf16. EPI=0: plain / split partials; EPI=1: gelu; EPI=2: qkv split.
template<int EPI, int SPLIT>
__global__ __launch_bounds__(256, 4) void gemm_bt_kernel(
    const u16* __restrict__ A, const u16* __restrict__ W,
    u16* __restrict__ Cb, u16* __restrict__ Vt,
    int M, int N, int K)
{
  __shared__ __align__(16) u16 LDSb[2][2][128 * 32];  // [buf][A/B][...] = 32KB
  const int tn = N >> 7, tm = M >> 7;
  int bid = blockIdx.x;
  const int nwg = gridDim.x;
  if ((nwg & 7) == 0) bid = (bid & 7) * (nwg >> 3) + (bid >> 3);  // XCD swizzle
  const int ts = tm * tn;
  const int sK = bid / ts;
  const int tb = bid - sK * ts;
  const int bm = tb / tn, bn = tb % tn;
  const int Kc = K / SPLIT;
  const int kbeg = sK * Kc;

  const int t = threadIdx.x, l = t & 63, w = t >> 6;
  const int wr = w >> 1, wc = w & 1;
  const int m0 = bm << 7, n0 = bn << 7;
  const int ssc = (((l & 3) ^ ((l >> 3) & 3)) << 3);
  const int srA = m0 + (w << 5) + (l >> 2);
  const int srB = n0 + (w << 5) + (l >> 2);
  const int ldso = (w << 10);
  const int fr = l & 15, g4 = l >> 4;
  const int fc8 = ((g4 ^ ((l >> 1) & 3)) << 3);

  f32x4 acc[4][4];
#pragma unroll
  for (int i = 0; i < 4; ++i)
#pragma unroll
    for (int j = 0; j < 4; ++j)
#pragma unroll
      for (int e = 0; e < 4; ++e) acc[i][j][e] = 0.f;

  const u16* pa0 = A + (size_t)srA * K + kbeg + ssc;
  const u16* pa1 = A + (size_t)(srA + 16) * K + kbeg + ssc;
  const u16* pb0 = W + (size_t)srB * K + kbeg + ssc;
  const u16* pb1 = W + (size_t)(srB + 16) * K + kbeg + ssc;

#define STAGE(buf, koff)                                   \
  do {                                                     \
    gload_lds16(pa0 + (koff), &LDSb[buf][0][ldso]);        \
    gload_lds16(pa1 + (koff), &LDSb[buf][0][ldso + 512]);  \
    gload_lds16(pb0 + (koff), &LDSb[buf][1][ldso]);        \
    gload_lds16(pb1 + (koff), &LDSb[buf][1][ldso + 512]);  \
  } while (0)

  const int nt = Kc >> 5;
  STAGE(0, 0);
  int cur = 0;
  for (int kt = 0; kt < nt; ++kt) {
    if (kt + 1 < nt) {
      STAGE(cur ^ 1, (kt + 1) << 5);
      asm volatile("s_waitcnt vmcnt(4)" ::: "memory");
    } else {
      asm volatile("s_waitcnt vmcnt(0)" ::: "memory");
    }
    __builtin_amdgcn_s_barrier();
    __builtin_amdgcn_sched_barrier(0);
    s16x8 af[4], bfr[4];
#pragma unroll
    for (int m = 0; m < 4; ++m)
      af[m] = *(const s16x8*)(&LDSb[cur][0][(wr * 64 + m * 16 + fr) * 32 + fc8]);
#pragma unroll
    for (int n = 0; n < 4; ++n)
      bfr[n] = *(const s16x8*)(&LDSb[cur][1][(wc * 64 + n * 16 + fr) * 32 + fc8]);
#pragma unroll
    for (int m = 0; m < 4; ++m)
#pragma unroll
      for (int n = 0; n < 4; ++n)
        acc[m][n] = __builtin_amdgcn_mfma_f32_16x16x32_bf16(af[m], bfr[n], acc[m][n], 0, 0, 0);
    asm volatile("s_waitcnt lgkmcnt(0)" ::: "memory");
    __builtin_amdgcn_sched_barrier(0);
    __builtin_amdgcn_s_barrier();
    cur ^= 1;
  }
#undef STAGE

  // -------- epilogue --------
  if (EPI == 2 && n0 >= 2048) {
    // V tile: transposed scatter (inherently non-coalesced on one side; ushort4 contiguous)
    const int rbv = m0 + wr * 64 + (g4 << 2);
    const int cbv = n0 + wc * 64 + fr;
#pragma unroll
    for (int m = 0; m < 4; ++m)
#pragma unroll
      for (int n = 0; n < 4; ++n) {
        int cc = cbv + n * 16 - 2048;
        int hh = cc >> 6, dd = cc & 63;
        int r0 = rbv + m * 16;
        ushort4 ov;
        ov.x = f2bf(acc[m][n][0]); ov.y = f2bf(acc[m][n][1]);
        ov.z = f2bf(acc[m][n][2]); ov.w = f2bf(acc[m][n][3]);
        *(ushort4*)&Vt[((size_t)((r0 >> 10) * 16 + hh) * 64 + dd) * 1024 + (r0 & 1023)] = ov;
      }
    return;
  }

  // LDS transpose: 2 rounds x 64 rows. scr[64][128] f32 = 32KB (reuses LDSb).
  float* scr = (float*)LDSb;
  const int strideN = (EPI == 2) ? 2048 : N;
  u16* Cout = (SPLIT > 1) ? (Cb + (size_t)sK * M * N) : Cb;
#pragma unroll
  for (int r = 0; r < 2; ++r) {
    __syncthreads();
    if (wr == r) {
#pragma unroll
      for (int m = 0; m < 4; ++m)
#pragma unroll
        for (int n = 0; n < 4; ++n)
#pragma unroll
          for (int j = 0; j < 4; ++j) {
            int lr = m * 16 + (g4 << 2) + j;
            int col = wc * 64 + n * 16 + fr;
            scr[lr * 128 + (col ^ ((((lr >> 2) & 7)) << 3))] = acc[m][n][j];
          }
    }
    __syncthreads();
#pragma unroll
    for (int it = 0; it < 4; ++it) {
      int lr = it * 16 + (t >> 4);
      int key8 = ((lr >> 2) & 7) << 3;
      int lc = (t & 15) << 3;
      int cb0 = (lc ^ key8);
      f32x4 v0 = *(const f32x4*)&scr[lr * 128 + cb0];
      f32x4 v1 = *(const f32x4*)&scr[lr * 128 + cb0 + 4];
      float vv[8] = {v0[0], v0[1], v0[2], v0[3], v1[0], v1[1], v1[2], v1[3]};
      s16x8 ov;
#pragma unroll
      for (int c = 0; c < 8; ++c) {
        float v = vv[c];
        if (EPI == 1) v = 0.5f * v * (1.f + erff(v * 0.70710678118f));
        ov[c] = (short)f2bf(v);
      }
      size_t gr = (size_t)(m0 + r * 64 + lr);
      *(s16x8*)&Cout[gr * strideN + n0 + lc] = ov;
    }
  }
}

// ---------------- MFMA flash attention, causal ----------------
__global__ __launch_bounds__(256) void attn_mfma_kernel(
    const u16* __restrict__ qk, const u16* __restrict__ Vt, u16* __restrict__ out)
{
  const int h = blockIdx.y, b = blockIdx.z;
  const int qt = (h & 1) ? (15 - blockIdx.x) : blockIdx.x;
  const int t = threadIdx.x, l = t & 63, w = t >> 6;
  const int q0 = qt << 6;
  __shared__ __align__(16) u16 Ks[64 * 64];
  __shared__ __align__(16) u16 Vs[64 * 64];
  __shared__ __align__(16) u16 Ps[4][16 * 64];

  const int fr = l & 15;
  const int fg = (l >> 4) << 3;
  const int fswz = (fr & 7) << 3;

  const int qrow = q0 + w * 16 + fr;
  const size_t qbase = (size_t)(b * 1024 + qrow) * 2048 + h * 64 + fg;
  const s16x8 aq0 = *(const s16x8*)(qk + qbase);
  const s16x8 aq1 = *(const s16x8*)(qk + qbase + 32);

  f32x4 acc_o[4];
#pragma unroll
  for (int i = 0; i < 4; ++i)
#pragma unroll
    for (int e = 0; e < 4; ++e) acc_o[i][e] = 0.f;
  float m_i[4] = {-INFINITY, -INFINITY, -INFINITY, -INFINITY};
  float l_i[4] = {0.f, 0.f, 0.f, 0.f};

  const int srow = t >> 2;
  const int sc = (t & 3) << 4;
  const int c0s = sc ^ ((srow & 7) << 3);
  const int c1s = (sc + 8) ^ ((srow & 7) << 3);
  const int qrow_c = q0 + w * 16 + ((l >> 4) << 2);
  u16* Psw = &Ps[w][0];
  const int nkt = qt + 1;

  for (int kt = 0; kt < nkt; ++kt) {
    const int kb = kt << 6;
    __syncthreads();
    {
      size_t kg = (size_t)(b * 1024 + kb + srow) * 2048 + 1024 + h * 64 + sc;
      s16x8 kv0 = *(const s16x8*)(qk + kg);
      s16x8 kv1 = *(const s16x8*)(qk + kg + 8);
      size_t vg = (size_t)((b * 16 + h) * 64 + srow) * 1024 + kb + sc;
      s16x8 vv0 = *(const s16x8*)(Vt + vg);
      s16x8 vv1 = *(const s16x8*)(Vt + vg + 8);
      *(s16x8*)(Ks + srow * 64 + c0s) = kv0;
      *(s16x8*)(Ks + srow * 64 + c1s) = kv1;
      *(s16x8*)(Vs + srow * 64 + c0s) = vv0;
      *(s16x8*)(Vs + srow * 64 + c1s) = vv1;
    }
    __syncthreads();

    f32x4 s[4];
#pragma unroll
    for (int n = 0; n < 4; ++n) {
#pragma unroll
      for (int e = 0; e < 4; ++e) s[n][e] = 0.f;
      s16x8 bk0 = *(const s16x8*)(Ks + (n * 16 + fr) * 64 + (fg ^ fswz));
      s16x8 bk1 = *(const s16x8*)(Ks + (n * 16 + fr) * 64 + ((32 + fg) ^ fswz));
      s[n] = __builtin_amdgcn_mfma_f32_16x16x32_bf16(aq0, bk0, s[n], 0, 0, 0);
      s[n] = __builtin_amdgcn_mfma_f32_16x16x32_bf16(aq1, bk1, s[n], 0, 0, 0);
    }
#pragma unroll
    for (int n = 0; n < 4; ++n)
#pragma unroll
      for (int e = 0; e < 4; ++e) s[n][e] *= 0.125f;
    if (kt == qt) {
#pragma unroll
      for (int n = 0; n < 4; ++n) {
        int kc = kb + n * 16 + fr;
#pragma unroll
        for (int r = 0; r < 4; ++r)
          if (kc > qrow_c + r) s[n][r] = -INFINITY;
      }
    }

    float rm[4], fac[4];
#pragma unroll
    for (int r = 0; r < 4; ++r)
      rm[r] = fmaxf(fmaxf(s[0][r], s[1][r]), fmaxf(s[2][r], s[3][r]));
#pragma unroll
    for (int off = 1; off < 16; off <<= 1)
#pragma unroll
      for (int r = 0; r < 4; ++r) rm[r] = fmaxf(rm[r], __shfl_xor(rm[r], off));
#pragma unroll
    for (int r = 0; r < 4; ++r) {
      float mn = fmaxf(m_i[r], rm[r]);
      fac[r] = __expf(m_i[r] - mn);
      m_i[r] = mn;
    }
    float rs[4] = {0.f, 0.f, 0.f, 0.f};
    float pb[4][4];
#pragma unroll
    for (int n = 0; n < 4; ++n)
#pragma unroll
      for (int r = 0; r < 4; ++r) {
        float pv = __expf(s[n][r] - m_i[r]);
        pb[n][r] = pv;
        rs[r] += pv;
      }
#pragma unroll
    for (int off = 1; off < 16; off <<= 1)
#pragma unroll
      for (int r = 0; r < 4; ++r) rs[r] += __shfl_xor(rs[r], off);
#pragma unroll
    for (int r = 0; r < 4; ++r) l_i[r] = l_i[r] * fac[r] + rs[r];
#pragma unroll
    for (int dt = 0; dt < 4; ++dt)
#pragma unroll
      for (int r = 0; r < 4; ++r) acc_o[dt][r] *= fac[r];

#pragma unroll
    for (int n = 0; n < 4; ++n)
#pragma unroll
      for (int r = 0; r < 4; ++r) {
        int prow = ((l >> 4) << 2) + r;
        Psw[prow * 64 + ((n * 16 + fr) ^ ((prow & 7) << 3))] = f2bf(pb[n][r]);
      }
    asm volatile("s_waitcnt lgkmcnt(0)" ::: "memory");
    __builtin_amdgcn_sched_barrier(0);

    s16x8 pa0 = *(const s16x8*)(Psw + fr * 64 + (fg ^ fswz));
    s16x8 pa1 = *(const s16x8*)(Psw + fr * 64 + ((32 + fg) ^ fswz));
#pragma unroll
    for (int dt = 0; dt < 4; ++dt) {
      s16x8 bv0 = *(const s16x8*)(Vs + (dt * 16 + fr) * 64 + (fg ^ fswz));
      s16x8 bv1 = *(const s16x8*)(Vs + (dt * 16 + fr) * 64 + ((32 + fg) ^ fswz));
      acc_o[dt] = __builtin_amdgcn_mfma_f32_16x16x32_bf16(pa0, bv0, acc_o[dt], 0, 0, 0);
      acc_o[dt] = __builtin_amdgcn_mfma_f32_16x16x32_bf16(pa1, bv1, acc_o[dt], 0, 0, 0);
    }
  }

  float invl[4];
#pragma unroll
  for (int r = 0; r < 4; ++r) invl[r] = 1.f / l_i[r];
#pragma unroll
  for (int dt = 0; dt < 4; ++dt)
#pragma unroll
    for (int r = 0; r < 4; ++r) {
      size_t idx = (size_t)(b * 1024 + qrow_c + r) * 1024 + h * 64 + dt * 16 + fr;
      out[idx] = f2bf(acc_o[dt][r] * invl[r]);
    }
}

// ---------------- final depth-2 (sums NPART bf16 partials + bf16 mixrest) ----------------
template<int NPART>
__global__ __launch_bounds__(256) void depth2_kernel(
    const u16* __restrict__ parts, const u16* __restrict__ mixrest,
    const float* __restrict__ beta, float* __restrict__ Hout)
{
  const size_t MN = (size_t)4096 * 1024;
  const size_t stride = (size_t)gridDim.x * 256;
  const size_t n8 = (size_t)BB * LL * RR * DD / 8;
  for (size_t i = (size_t)blockIdx.x * 256 + threadIdx.x; i < n8; i += stride) {
    size_t e = i * 8;
    int d = (int)(e & 1023);
    int n = (int)((e >> 10) & 3);
    size_t bl = e >> 12;
    float be = beta[bl * 4 + n];
    float f[8];
#pragma unroll
    for (int j = 0; j < 8; ++j) f[j] = 0.f;
#pragma unroll
    for (int p = 0; p < NPART; ++p) {
      s16x8 v = *(const s16x8*)&parts[p * MN + bl * 1024 + d];
#pragma unroll
      for (int j = 0; j < 8; ++j) f[j] += bf2f((u16)v[j]);
    }
    s16x8 m = *(const s16x8*)&mixrest[e];
    float4 o0, o1;
    o0.x = be * f[0] + bf2f((u16)m[0]); o0.y = be * f[1] + bf2f((u16)m[1]);
    o0.z = be * f[2] + bf2f((u16)m[2]); o0.w = be * f[3] + bf2f((u16)m[3]);
    o1.x = be * f[4] + bf2f((u16)m[4]); o1.y = be * f[5] + bf2f((u16)m[5]);
    o1.z = be * f[6] + bf2f((u16)m[6]); o1.w = be * f[7] + bf2f((u16)m[7]);
    *(float4*)&Hout[e] = o0;
    *(float4*)&Hout[e + 4] = o1;
  }
}

extern "C" void kernel_launch(void* const* d_in, const int* in_sizes, int n_in,
                              void* d_out, int out_size, void* d_ws, size_t ws_size,
                              hipStream_t stream) {
  const float* H       = (const float*)d_in[0];
  const float* hc1_nw  = (const float*)d_in[1];
  const float* hc1_afn = (const float*)d_in[2];
  const float* hc1_bfn = (const float*)d_in[3];
  const float* hc1_as  = (const float*)d_in[4];
  const float* hc1_bs  = (const float*)d_in[5];
  const float* hc1_sa  = (const float*)d_in[6];
  const float* hc1_sb  = (const float*)d_in[7];
  const float* attn_nw = (const float*)d_in[8];
  const float* qkv_w   = (const float*)d_in[9];
  const float* out_w   = (const float*)d_in[10];
  const float* hc2_nw  = (const float*)d_in[11];
  const float* hc2_afn = (const float*)d_in[12];
  const float* hc2_bfn = (const float*)d_in[13];
  const float* hc2_as  = (const float*)d_in[14];
  const float* hc2_bs  = (const float*)d_in[15];
  const float* hc2_sa  = (const float*)d_in[16];
  const float* hc2_sb  = (const float*)d_in[17];
  const float* ffn_nw  = (const float*)d_in[18];
  const float* fc1_w   = (const float*)d_in[19];
  const float* fc2_w   = (const float*)d_in[20];
  float* Hout = (float*)d_out;

  char* wsp = (char*)d_ws;
  size_t off = 0;
  auto carve = [&](size_t bytes) {
    void* p = wsp + off;
    off = (off + bytes + 255) & ~(size_t)255;
    return p;
  };
  const size_t MN = (size_t)4096 * 1024;
  u16* wq_bf   = (u16*)carve((size_t)3072 * 1024 * 2);
  u16* wo_bf   = (u16*)carve((size_t)1024 * 1024 * 2);
  u16* w1_bf   = (u16*)carve((size_t)4096 * 1024 * 2);
  u16* w2_bf   = (u16*)carve((size_t)4096 * 1024 * 2);
  u16* xbf     = (u16*)carve((size_t)4096 * 1024 * 2);
  u16* mixrest = (u16*)carve((size_t)4096 * 4096 * 2);
  float* beta1 = (float*)carve((size_t)16384 * 4);
  float* beta2 = (float*)carve((size_t)16384 * 4);
  char* uregion = (char*)carve((size_t)32 * 1024 * 1024);
  u16* qk_bf   = (u16*)uregion;
  u16* Vt      = (u16*)(uregion + (size_t)16 * 1024 * 1024);
  u16* g1_bf   = (u16*)uregion;
  u16* attn_bf = (u16*)carve((size_t)4096 * 1024 * 2);
  u16* pp      = (u16*)carve((size_t)4 * MN * 2);        // 4 bf16 partials

  // 1. weights -> bf16 (fused)
  cvt4_kernel<<<2048, 256, 0, stream>>>(qkv_w, out_w, fc1_w, fc2_w, wq_bf, wo_bf, w1_bf, w2_bf);
  // 2. width1 (+ pre-attn RMS)
  width_kernel<0><<<4096, 256, 0, stream>>>(H, nullptr, nullptr, nullptr,
      hc1_nw, hc1_afn, hc1_bfn, hc1_as, hc1_bs, hc1_sa, hc1_sb, attn_nw,
      mixrest, beta1, xbf);
  // 3. qkv -> bf16 Q,K + transposed V (768 blocks, 3/CU)
  gemm_bt_kernel<2, 1><<<768, 256, 0, stream>>>(xbf, wq_bf, qk_bf, Vt, 4096, 3072, 1024);
  // 4. attention (MFMA flash)
  attn_mfma_kernel<<<dim3(16, 16, 4), 256, 0, stream>>>(qk_bf, Vt, attn_bf);
  // 5. out projection, split-K=4 -> bf16 partials (1024 blocks, 4/CU)
  gemm_bt_kernel<0, 4><<<1024, 256, 0, stream>>>(attn_bf, wo_bf, pp, nullptr, 4096, 1024, 1024);
  // 6. depth1 + width2 (+ pre-ffn RMS); mixrest in-place
  width_kernel<4><<<4096, 256, 0, stream>>>(nullptr, mixrest, beta1, pp,
      hc2_nw, hc2_afn, hc2_bfn, hc2_as, hc2_bs, hc2_sa, hc2_sb, ffn_nw,
      mixrest, beta2, xbf);
  // 7. fc1 + gelu -> bf16 (1024 blocks, 4/CU)
  gemm_bt_kernel<1, 1><<<1024, 256, 0, stream>>>(xbf, w1_bf, g1_bf, nullptr, 4096, 4096, 1024);
  // 8. fc2, split-K=4 -> bf16 partials (1024 blocks, 4/CU)
  gemm_bt_kernel<0, 4><<<1024, 256, 0, stream>>>(g1_bf, w2_bf, pp, nullptr, 4096, 1024, 4096);
  // 9. depth2 -> output
  depth2_kernel<4><<<4096, 256, 0, stream>>>(pp, mixrest, beta2, Hout);
}